// Round 1
// 7155.401 us; speedup vs baseline: 1.0764x; 1.0764x over previous
//
#include <hip/hip_runtime.h>

typedef unsigned short u16;
typedef unsigned int   u32;
typedef unsigned long long u64;
typedef __attribute__((ext_vector_type(8))) short bf16x8;
typedef __attribute__((ext_vector_type(4))) float f32x4;

// ---------- helpers ----------
__device__ __forceinline__ u16 f2bf(float f) {
    u32 u; __builtin_memcpy(&u, &f, 4);
    u32 r = (u + 0x7FFFu + ((u >> 16) & 1u)) >> 16;   // RTNE
    return (u16)r;
}
__device__ __forceinline__ float bf2f(u16 h) {
    u32 u = ((u32)h) << 16; float f; __builtin_memcpy(&f, &u, 4); return f;
}
__device__ __forceinline__ float sigmoidf(float x) { return 1.f / (1.f + __expf(-x)); }
__device__ __forceinline__ float tanh_safe(float x) {
    float e = __expf(-2.f * fabsf(x));
    float t = (1.f - e) / (1.f + e);
    return x >= 0.f ? t : -t;
}

// ---------- fp32 -> bf16 hi/lo split (weights: removes systematic rounding) ----------
__global__ __launch_bounds__(256) void castk2(const float* __restrict__ s, u16* __restrict__ hi,
                                              u16* __restrict__ lo, int n) {
    int i = blockIdx.x * 256 + threadIdx.x;
    if (i < n) {
        float f = s[i];
        u16 h = f2bf(f);
        hi[i] = h;
        lo[i] = f2bf(f - bf2f(h));
    }
}

// ---------- embedding gather + cast ----------
__global__ __launch_bounds__(256) void embed_cast(const int* __restrict__ x, const float* __restrict__ emb,
                                                  u16* __restrict__ x0) {
    int m = blockIdx.x;
    int idx = x[m];
    const float2* src = (const float2*)(emb + (size_t)idx * 512);
    u16* dst = x0 + (size_t)m * 512;
    int t = threadIdx.x;
    float2 v = src[t];
    dst[t * 2]     = f2bf(v.x);
    dst[t * 2 + 1] = f2bf(v.y);
}

// ---------- C[M,N] = A[M,K] @ (Bhi+Blo)[N,K]^T, bf16 A, split-bf16 B, bf16 out, fp32 accum ----------
__global__ __launch_bounds__(256) void gemm_bt(const u16* __restrict__ A, const u16* __restrict__ Bhi,
                                               const u16* __restrict__ Blo,
                                               u16* __restrict__ C, int M, int N, int K) {
    __shared__ __align__(16) u16 sA[128 * 32];
    __shared__ __align__(16) u16 sBh[128 * 32];
    __shared__ __align__(16) u16 sBl[128 * 32];
    const int tid  = threadIdx.x;
    const int lane = tid & 63, wave = tid >> 6;
    const int m0 = blockIdx.y * 128, n0 = blockIdx.x * 128;
    const int wm = (wave >> 1) * 64, wn = (wave & 1) * 64;
    f32x4 acc[4][4] = {};

    const int r0 = tid >> 2, c8 = (tid & 3) * 8;
    const int r1 = r0 + 64;
    const u16* Ap   = A   + (size_t)(m0 + r0) * K + c8;
    const u16* Ap2  = A   + (size_t)(m0 + r1) * K + c8;
    const u16* Bhp  = Bhi + (size_t)(n0 + r0) * K + c8;
    const u16* Bhp2 = Bhi + (size_t)(n0 + r1) * K + c8;
    const u16* Blp  = Blo + (size_t)(n0 + r0) * K + c8;
    const u16* Blp2 = Blo + (size_t)(n0 + r1) * K + c8;

    uint4 ra0, ra1, rh0, rh1, rl0, rl1;
    ra0 = *(const uint4*)(Ap);   ra1 = *(const uint4*)(Ap2);
    rh0 = *(const uint4*)(Bhp);  rh1 = *(const uint4*)(Bhp2);
    rl0 = *(const uint4*)(Blp);  rl1 = *(const uint4*)(Blp2);

    for (int kk = 0; kk < K; kk += 32) {
        __syncthreads();
        *(uint4*)(sA  + tid * 8)        = ra0;
        *(uint4*)(sA  + 2048 + tid * 8) = ra1;
        *(uint4*)(sBh + tid * 8)        = rh0;
        *(uint4*)(sBh + 2048 + tid * 8) = rh1;
        *(uint4*)(sBl + tid * 8)        = rl0;
        *(uint4*)(sBl + 2048 + tid * 8) = rl1;
        int kn = kk + 32;
        if (kn < K) {
            ra0 = *(const uint4*)(Ap + kn);   ra1 = *(const uint4*)(Ap2 + kn);
            rh0 = *(const uint4*)(Bhp + kn);  rh1 = *(const uint4*)(Bhp2 + kn);
            rl0 = *(const uint4*)(Blp + kn);  rl1 = *(const uint4*)(Blp2 + kn);
        }
        __syncthreads();
        bf16x8 av[4], bh[4], bl[4];
#pragma unroll
        for (int i = 0; i < 4; ++i) {
            av[i] = *(const bf16x8*)(sA  + (wm + i * 16 + (lane & 15)) * 32 + (lane >> 4) * 8);
            bh[i] = *(const bf16x8*)(sBh + (wn + i * 16 + (lane & 15)) * 32 + (lane >> 4) * 8);
            bl[i] = *(const bf16x8*)(sBl + (wn + i * 16 + (lane & 15)) * 32 + (lane >> 4) * 8);
        }
#pragma unroll
        for (int i = 0; i < 4; ++i)
#pragma unroll
            for (int j = 0; j < 4; ++j) {
                acc[i][j] = __builtin_amdgcn_mfma_f32_16x16x32_bf16(av[i], bh[j], acc[i][j], 0, 0, 0);
                acc[i][j] = __builtin_amdgcn_mfma_f32_16x16x32_bf16(av[i], bl[j], acc[i][j], 0, 0, 0);
            }
    }
#pragma unroll
    for (int i = 0; i < 4; ++i) {
        int m = m0 + wm + i * 16 + ((lane >> 4) << 2);
#pragma unroll
        for (int j = 0; j < 4; ++j) {
            int n = n0 + wn + j * 16 + (lane & 15);
#pragma unroll
            for (int rr = 0; rr < 4; ++rr)
                C[(size_t)(m + rr) * N + n] = f2bf(acc[i][j][rr]);
        }
    }
}

// ---------- persistent bidirectional LSTM recurrence, one layer ----------
// grid = 128 blocks: dir = blockIdx>>6, slice = blockIdx&63 -> hidden units [slice*8, slice*8+8)
// Whh slice resident in VGPRs as hi/lo MFMA B-fragments. h exchanged as hi/lo bf16 planes via
// LLC (agent-scope atomics), double-buffered.
// Sync: per-slice monotonic flag (store/load) instead of a single fetch_add counter —
// 64 same-address RMWs serialize at the coherence point; 64 parallel flag stores do not.
// Consumer: wave 0 polls all 64 flags with one wave-wide load + __all.
// Producer: wave 0 alone publishes the 1 KiB slice, then lane 0 release-stores the flag
// (release waits the wave's own vmcnt(0) -> no cross-wave barrier on the signal path).
template <int LAYER>
__global__ __launch_bounds__(256, 1) void lstm_rec(
    const u16* __restrict__ xp_f, const u16* __restrict__ xp_b,
    const u16* __restrict__ whh_f_hi, const u16* __restrict__ whh_f_lo,
    const u16* __restrict__ whh_b_hi, const u16* __restrict__ whh_b_lo,
    const float* __restrict__ bih_f, const float* __restrict__ bhh_f,
    const float* __restrict__ bih_b, const float* __restrict__ bhh_b,
    u16* __restrict__ out0, float* __restrict__ pooled, const int* __restrict__ mask,
    u16* hbuf, u32* cnt)
{
    const int HP = 520;                              // padded LDS row (u16 units)
    __shared__ __align__(16) u16  sHhi[32 * 520];    // h hi plane
    __shared__ __align__(16) u16  sHlo[32 * 520];    // h lo plane
    __shared__ __align__(16) u16  sXp[32 * 32];      // xp tile for this step
    __shared__ __align__(16) float sG[32 * 33];      // gate pre-activations
    __shared__ __align__(16) u16  sHoutHi[32 * 8];
    __shared__ __align__(16) u16  sHoutLo[32 * 8];

    const int tid = threadIdx.x;
    const int dir = blockIdx.x >> 6;
    const int slice = blockIdx.x & 63;
    const u16* xp     = dir ? xp_b : xp_f;
    const u16* whhH   = dir ? whh_b_hi : whh_f_hi;
    const u16* whhL   = dir ? whh_b_lo : whh_f_lo;
    const float* bih  = dir ? bih_b : bih_f;
    const float* bhh  = dir ? bhh_b : bhh_f;
    // per dir: 2 bufs x 2 planes x 32*512 u16
    u16* hbD = hbuf + dir * 65536;
    u32* myFlags = cnt + dir * 64;                   // 64 per-slice monotonic flags

    const int wave = tid >> 6, lane = tid & 63;
    const int wm = (wave >> 1) * 16;          // batch half
    const int wn = (wave & 1) * 16;           // gate-col half
    bf16x8 wfragH[16], wfragL[16];
    {
        int n = wn + (lane & 15);
        int q = n >> 3, rr = n & 7;
        size_t rowoff = (size_t)(q * 512 + slice * 8 + rr) * 512 + (lane >> 4) * 8;
        const u16* wrh = whhH + rowoff;
        const u16* wrl = whhL + rowoff;
#pragma unroll
        for (int k2 = 0; k2 < 16; ++k2) {
            wfragH[k2] = *(const bf16x8*)(wrh + k2 * 32);
            wfragL[k2] = *(const bf16x8*)(wrl + k2 * 32);
        }
    }
    const int b = tid >> 3, r = tid & 7;      // cell-phase mapping
    float bias[4];
#pragma unroll
    for (int q = 0; q < 4; ++q) {
        int g = q * 512 + slice * 8 + r;
        bias[q] = bih[g] + bhh[g];
    }
    float cstate = 0.f, pool = 0.f;
    const int aoff = (wm + (lane & 15)) * HP + (lane >> 4) * 8;
    const int gRow = wm + ((lane >> 4) << 2), gCol = wn + (lane & 15);
    const int srow = tid >> 3, sc = tid & 7;  // stage mapping

    for (int t = 0; t < 512; ++t) {
        const int tt = dir ? (511 - t) : t;
        // 1. stage xp tile (independent of h; overlaps the flag wait)
        if (tid < 128) {
            int xb = tid >> 2, xq = tid & 3;
            const uint4 v = *(const uint4*)(xp + ((size_t)(xb * 512 + tt)) * 2048 + xq * 512 + slice * 8);
            *(uint4*)(sXp + xb * 32 + xq * 8) = v;
        }
        // 2. wave 0 polls all 64 slice flags of this dir for h_{t-1}
        if (t > 0 && tid < 64) {
            const u32 tgt = (u32)t;
            for (;;) {
                u32 v = __hip_atomic_load(myFlags + tid, __ATOMIC_RELAXED, __HIP_MEMORY_SCOPE_AGENT);
                if (__all((int)(v >= tgt))) break;
                __builtin_amdgcn_s_sleep(1);
            }
        }
        __syncthreads();                       // B1: xp staged + all h_{t-1} published
        if (t > 0) {
            // 3. stage h hi/lo planes: issue ALL 32 loads first, then all LDS writes
            //    (guarantees one LLC latency exposure instead of 8 serialized rounds)
            const u16* hp = hbD + ((t - 1) & 1) * 32768 + srow * 512;   // hi plane row
            const u16* lp = hp + 16384;                                  // lo plane row
            u16* dhi = sHhi + srow * HP;
            u16* dlo = sHlo + srow * HP;
            u64 rh[16], rl[16];
#pragma unroll
            for (int j = 0; j < 8; ++j) {
                int ch = sc + 8 * j;              // chunk of 8 u16 (16B)
                rh[2*j]   = __hip_atomic_load((const u64*)(hp + ch * 8),     __ATOMIC_RELAXED, __HIP_MEMORY_SCOPE_AGENT);
                rh[2*j+1] = __hip_atomic_load((const u64*)(hp + ch * 8) + 1, __ATOMIC_RELAXED, __HIP_MEMORY_SCOPE_AGENT);
                rl[2*j]   = __hip_atomic_load((const u64*)(lp + ch * 8),     __ATOMIC_RELAXED, __HIP_MEMORY_SCOPE_AGENT);
                rl[2*j+1] = __hip_atomic_load((const u64*)(lp + ch * 8) + 1, __ATOMIC_RELAXED, __HIP_MEMORY_SCOPE_AGENT);
            }
#pragma unroll
            for (int j = 0; j < 8; ++j) {
                int ch = sc + 8 * j;
                *(u64*)(dhi + ch * 8)     = rh[2*j];
                *(u64*)(dhi + ch * 8 + 4) = rh[2*j+1];
                *(u64*)(dlo + ch * 8)     = rl[2*j];
                *(u64*)(dlo + ch * 8 + 4) = rl[2*j+1];
            }
        }
        __syncthreads();                       // B2: h staged
        // 4. G = h @ Whh_slice^T with hi/lo split (skip t=0: h0=0)
        f32x4 acc = {};
        if (t > 0) {
#pragma unroll
            for (int k2 = 0; k2 < 16; ++k2) {
                bf16x8 ah = *(const bf16x8*)(sHhi + aoff + k2 * 32);
                bf16x8 al = *(const bf16x8*)(sHlo + aoff + k2 * 32);
                acc = __builtin_amdgcn_mfma_f32_16x16x32_bf16(ah, wfragH[k2], acc, 0, 0, 0);
                acc = __builtin_amdgcn_mfma_f32_16x16x32_bf16(al, wfragH[k2], acc, 0, 0, 0);
                acc = __builtin_amdgcn_mfma_f32_16x16x32_bf16(ah, wfragL[k2], acc, 0, 0, 0);
            }
        }
#pragma unroll
        for (int rr = 0; rr < 4; ++rr) sG[(gRow + rr) * 33 + gCol] = acc[rr];
        __syncthreads();                       // B3: gates ready
        // 5. LSTM cell (fp32)
        {
            float gq[4];
#pragma unroll
            for (int q = 0; q < 4; ++q)
                gq[q] = sG[b * 33 + q * 8 + r] + bf2f(sXp[b * 32 + q * 8 + r]) + bias[q];
            float ig = sigmoidf(gq[0]), fg = sigmoidf(gq[1]);
            float gg = tanh_safe(gq[2]), og = sigmoidf(gq[3]);
            cstate = fg * cstate + ig * gg;
            float h = og * tanh_safe(cstate);
            u16 hh = f2bf(h);
            if (LAYER == 0) {
                out0[((size_t)(b * 512 + tt)) * 1024 + dir * 512 + slice * 8 + r] = hh;
            } else {
                pool += h * (float)mask[b * 512 + tt];
            }
            sHoutHi[b * 8 + r] = hh;
            sHoutLo[b * 8 + r] = f2bf(h - bf2f(hh));
        }
        __syncthreads();                       // B4: sHout ready for wave 0
        // 6. publish h slice (both planes) from wave 0 only, then release-store flag.
        //    Release waits this wave's vmcnt(0) -> covers all publish stores; other
        //    waves proceed straight to the next iteration (no trailing barrier).
        if (tid < 64) {
#pragma unroll
            for (int j = 0; j < 2; ++j) {
                int w = tid + 64 * j;              // u32 word over the 256-elem slice
                int pb = w >> 2, d = w & 3;
                u32 vh = ((const u32*)sHoutHi)[w];
                u32 vl = ((const u32*)sHoutLo)[w];
                u32* gh = (u32*)(hbD + (t & 1) * 32768 + pb * 512 + slice * 8) + d;
                u32* gl = (u32*)(hbD + (t & 1) * 32768 + 16384 + pb * 512 + slice * 8) + d;
                __hip_atomic_store(gh, vh, __ATOMIC_RELAXED, __HIP_MEMORY_SCOPE_AGENT);
                __hip_atomic_store(gl, vl, __ATOMIC_RELAXED, __HIP_MEMORY_SCOPE_AGENT);
            }
            if (tid == 0)
                __hip_atomic_store(myFlags + slice, (u32)(t + 1), __ATOMIC_RELEASE, __HIP_MEMORY_SCOPE_AGENT);
        }
    }
    if (LAYER == 1)
        pooled[(size_t)b * 1024 + dir * 512 + slice * 8 + r] = pool;
}

// ---------- final: logits = (pooled/msum) @ fcW^T + fcb ----------
__global__ __launch_bounds__(256) void final_fc(const float* __restrict__ pooled, const int* __restrict__ mask,
                                                const float* __restrict__ fcW, const float* __restrict__ fcb,
                                                float* __restrict__ out) {
    __shared__ float red[256];
    int tid = threadIdx.x;
    int pair = tid & 63, kc = tid >> 6;
    int b = pair >> 1, c = pair & 1;
    float s = 0.f;
    for (int k = kc * 256; k < kc * 256 + 256; ++k)
        s += pooled[b * 1024 + k] * fcW[c * 1024 + k];
    red[tid] = s;
    __syncthreads();
    if (kc == 0) {
        float tot = red[pair] + red[64 + pair] + red[128 + pair] + red[192 + pair];
        float ms = 0.f;
        for (int t = 0; t < 512; ++t) ms += (float)mask[b * 512 + t];
        ms = fmaxf(ms, 1e-9f);
        out[b * 2 + c] = tot / ms + fcb[c];
    }
}

extern "C" void kernel_launch(void* const* d_in, const int* in_sizes, int n_in,
                              void* d_out, int out_size, void* d_ws, size_t ws_size,
                              hipStream_t stream) {
    (void)in_sizes; (void)n_in; (void)out_size; (void)ws_size;
    const int*   x     = (const int*)d_in[0];
    const int*   amask = (const int*)d_in[1];
    const float* emb   = (const float*)d_in[2];
    const float* fcW   = (const float*)d_in[3];
    const float* fcb   = (const float*)d_in[4];
    const float* fWih0 = (const float*)d_in[5];
    const float* fWhh0 = (const float*)d_in[6];
    const float* fbih0 = (const float*)d_in[7];
    const float* fbhh0 = (const float*)d_in[8];
    const float* bWih0 = (const float*)d_in[9];
    const float* bWhh0 = (const float*)d_in[10];
    const float* bbih0 = (const float*)d_in[11];
    const float* bbhh0 = (const float*)d_in[12];
    const float* fWih1 = (const float*)d_in[13];
    const float* fWhh1 = (const float*)d_in[14];
    const float* fbih1 = (const float*)d_in[15];
    const float* fbhh1 = (const float*)d_in[16];
    const float* bWih1 = (const float*)d_in[17];
    const float* bWhh1 = (const float*)d_in[18];
    const float* bbih1 = (const float*)d_in[19];
    const float* bbhh1 = (const float*)d_in[20];

    char* ws = (char*)d_ws;
    size_t off = 0;
    auto alloc = [&](size_t bytes) { void* p = ws + off; off += (bytes + 1023) & ~(size_t)1023; return p; };
    u16* x0    = (u16*)alloc((size_t)16384 * 512 * 2);
    u16* xpf   = (u16*)alloc((size_t)16384 * 2048 * 2);
    u16* xpb   = (u16*)alloc((size_t)16384 * 2048 * 2);
    u16* out0  = (u16*)alloc((size_t)16384 * 1024 * 2);
    u16* wih0fH = (u16*)alloc((size_t)2048 * 512 * 2);
    u16* wih0fL = (u16*)alloc((size_t)2048 * 512 * 2);
    u16* wih0bH = (u16*)alloc((size_t)2048 * 512 * 2);
    u16* wih0bL = (u16*)alloc((size_t)2048 * 512 * 2);
    u16* whh0fH = (u16*)alloc((size_t)2048 * 512 * 2);
    u16* whh0fL = (u16*)alloc((size_t)2048 * 512 * 2);
    u16* whh0bH = (u16*)alloc((size_t)2048 * 512 * 2);
    u16* whh0bL = (u16*)alloc((size_t)2048 * 512 * 2);
    u16* wih1fH = (u16*)alloc((size_t)2048 * 1024 * 2);
    u16* wih1fL = (u16*)alloc((size_t)2048 * 1024 * 2);
    u16* wih1bH = (u16*)alloc((size_t)2048 * 1024 * 2);
    u16* wih1bL = (u16*)alloc((size_t)2048 * 1024 * 2);
    u16* whh1fH = (u16*)alloc((size_t)2048 * 512 * 2);
    u16* whh1fL = (u16*)alloc((size_t)2048 * 512 * 2);
    u16* whh1bH = (u16*)alloc((size_t)2048 * 512 * 2);
    u16* whh1bL = (u16*)alloc((size_t)2048 * 512 * 2);
    float* pooled = (float*)alloc((size_t)32 * 1024 * 4);
    u16* hbuf  = (u16*)alloc((size_t)2 * 2 * 2 * 32 * 512 * 2);   // dirs x bufs x planes
    u32* cnt   = (u32*)alloc(1024);                               // per-slice flags, 2 layers x 2 dirs x 64

    hipMemsetAsync(cnt, 0, 1024, stream);

    const int NW0 = 2048 * 512, NW1 = 2048 * 1024;
    castk2<<<dim3((NW0 + 255) / 256), 256, 0, stream>>>(fWih0, wih0fH, wih0fL, NW0);
    castk2<<<dim3((NW0 + 255) / 256), 256, 0, stream>>>(bWih0, wih0bH, wih0bL, NW0);
    castk2<<<dim3((NW0 + 255) / 256), 256, 0, stream>>>(fWhh0, whh0fH, whh0fL, NW0);
    castk2<<<dim3((NW0 + 255) / 256), 256, 0, stream>>>(bWhh0, whh0bH, whh0bL, NW0);
    castk2<<<dim3((NW1 + 255) / 256), 256, 0, stream>>>(fWih1, wih1fH, wih1fL, NW1);
    castk2<<<dim3((NW1 + 255) / 256), 256, 0, stream>>>(bWih1, wih1bH, wih1bL, NW1);
    castk2<<<dim3((NW0 + 255) / 256), 256, 0, stream>>>(fWhh1, whh1fH, whh1fL, NW0);
    castk2<<<dim3((NW0 + 255) / 256), 256, 0, stream>>>(bWhh1, whh1bH, whh1bL, NW0);

    embed_cast<<<dim3(16384), 256, 0, stream>>>(x, emb, x0);

    // layer 0 input projections: [16384,512] @ [2048,512]^T
    gemm_bt<<<dim3(16, 128), 256, 0, stream>>>(x0, wih0fH, wih0fL, xpf, 16384, 2048, 512);
    gemm_bt<<<dim3(16, 128), 256, 0, stream>>>(x0, wih0bH, wih0bL, xpb, 16384, 2048, 512);
    // layer 0 recurrence
    lstm_rec<0><<<dim3(128), 256, 0, stream>>>(xpf, xpb, whh0fH, whh0fL, whh0bH, whh0bL,
                                               fbih0, fbhh0, bbih0, bbhh0,
                                               out0, nullptr, nullptr, hbuf, cnt);
    // layer 1 input projections: [16384,1024] @ [2048,1024]^T
    gemm_bt<<<dim3(16, 128), 256, 0, stream>>>(out0, wih1fH, wih1fL, xpf, 16384, 2048, 1024);
    gemm_bt<<<dim3(16, 128), 256, 0, stream>>>(out0, wih1bH, wih1bL, xpb, 16384, 2048, 1024);
    // layer 1 recurrence + pooling
    lstm_rec<1><<<dim3(128), 256, 0, stream>>>(xpf, xpb, whh1fH, whh1fL, whh1bH, whh1bL,
                                               fbih1, fbhh1, bbih1, bbhh1,
                                               nullptr, pooled, amask, hbuf, cnt + 128);

    final_fc<<<dim3(1), 256, 0, stream>>>(pooled, amask, fcW, fcb, (float*)d_out);
}

// Round 2
// 6385.364 us; speedup vs baseline: 1.2062x; 1.1206x over previous
//
#include <hip/hip_runtime.h>

typedef unsigned short u16;
typedef unsigned int   u32;
typedef unsigned long long u64;
typedef __attribute__((ext_vector_type(8))) short bf16x8;
typedef __attribute__((ext_vector_type(4))) float f32x4;

// ---------- helpers ----------
__device__ __forceinline__ u16 f2bf(float f) {
    u32 u; __builtin_memcpy(&u, &f, 4);
    u32 r = (u + 0x7FFFu + ((u >> 16) & 1u)) >> 16;   // RTNE
    return (u16)r;
}
__device__ __forceinline__ float bf2f(u16 h) {
    u32 u = ((u32)h) << 16; float f; __builtin_memcpy(&f, &u, 4); return f;
}
__device__ __forceinline__ float sigmoidf(float x) { return 1.f / (1.f + __expf(-x)); }
__device__ __forceinline__ float tanh_safe(float x) {
    float e = __expf(-2.f * fabsf(x));
    float t = (1.f - e) / (1.f + e);
    return x >= 0.f ? t : -t;
}

// ---------- fp32 -> bf16 hi/lo split (weights: removes systematic rounding) ----------
__global__ __launch_bounds__(256) void castk2(const float* __restrict__ s, u16* __restrict__ hi,
                                              u16* __restrict__ lo, int n) {
    int i = blockIdx.x * 256 + threadIdx.x;
    if (i < n) {
        float f = s[i];
        u16 h = f2bf(f);
        hi[i] = h;
        lo[i] = f2bf(f - bf2f(h));
    }
}

// ---------- embedding gather + cast ----------
__global__ __launch_bounds__(256) void embed_cast(const int* __restrict__ x, const float* __restrict__ emb,
                                                  u16* __restrict__ x0) {
    int m = blockIdx.x;
    int idx = x[m];
    const float2* src = (const float2*)(emb + (size_t)idx * 512);
    u16* dst = x0 + (size_t)m * 512;
    int t = threadIdx.x;
    float2 v = src[t];
    dst[t * 2]     = f2bf(v.x);
    dst[t * 2 + 1] = f2bf(v.y);
}

// ---------- C[M,N] = A[M,K] @ (Bhi+Blo)[N,K]^T, bf16 A, split-bf16 B, bf16 out, fp32 accum ----------
__global__ __launch_bounds__(256) void gemm_bt(const u16* __restrict__ A, const u16* __restrict__ Bhi,
                                               const u16* __restrict__ Blo,
                                               u16* __restrict__ C, int M, int N, int K) {
    __shared__ __align__(16) u16 sA[128 * 32];
    __shared__ __align__(16) u16 sBh[128 * 32];
    __shared__ __align__(16) u16 sBl[128 * 32];
    const int tid  = threadIdx.x;
    const int lane = tid & 63, wave = tid >> 6;
    const int m0 = blockIdx.y * 128, n0 = blockIdx.x * 128;
    const int wm = (wave >> 1) * 64, wn = (wave & 1) * 64;
    f32x4 acc[4][4] = {};

    const int r0 = tid >> 2, c8 = (tid & 3) * 8;
    const int r1 = r0 + 64;
    const u16* Ap   = A   + (size_t)(m0 + r0) * K + c8;
    const u16* Ap2  = A   + (size_t)(m0 + r1) * K + c8;
    const u16* Bhp  = Bhi + (size_t)(n0 + r0) * K + c8;
    const u16* Bhp2 = Bhi + (size_t)(n0 + r1) * K + c8;
    const u16* Blp  = Blo + (size_t)(n0 + r0) * K + c8;
    const u16* Blp2 = Blo + (size_t)(n0 + r1) * K + c8;

    uint4 ra0, ra1, rh0, rh1, rl0, rl1;
    ra0 = *(const uint4*)(Ap);   ra1 = *(const uint4*)(Ap2);
    rh0 = *(const uint4*)(Bhp);  rh1 = *(const uint4*)(Bhp2);
    rl0 = *(const uint4*)(Blp);  rl1 = *(const uint4*)(Blp2);

    for (int kk = 0; kk < K; kk += 32) {
        __syncthreads();
        *(uint4*)(sA  + tid * 8)        = ra0;
        *(uint4*)(sA  + 2048 + tid * 8) = ra1;
        *(uint4*)(sBh + tid * 8)        = rh0;
        *(uint4*)(sBh + 2048 + tid * 8) = rh1;
        *(uint4*)(sBl + tid * 8)        = rl0;
        *(uint4*)(sBl + 2048 + tid * 8) = rl1;
        int kn = kk + 32;
        if (kn < K) {
            ra0 = *(const uint4*)(Ap + kn);   ra1 = *(const uint4*)(Ap2 + kn);
            rh0 = *(const uint4*)(Bhp + kn);  rh1 = *(const uint4*)(Bhp2 + kn);
            rl0 = *(const uint4*)(Blp + kn);  rl1 = *(const uint4*)(Blp2 + kn);
        }
        __syncthreads();
        bf16x8 av[4], bh[4], bl[4];
#pragma unroll
        for (int i = 0; i < 4; ++i) {
            av[i] = *(const bf16x8*)(sA  + (wm + i * 16 + (lane & 15)) * 32 + (lane >> 4) * 8);
            bh[i] = *(const bf16x8*)(sBh + (wn + i * 16 + (lane & 15)) * 32 + (lane >> 4) * 8);
            bl[i] = *(const bf16x8*)(sBl + (wn + i * 16 + (lane & 15)) * 32 + (lane >> 4) * 8);
        }
#pragma unroll
        for (int i = 0; i < 4; ++i)
#pragma unroll
            for (int j = 0; j < 4; ++j) {
                acc[i][j] = __builtin_amdgcn_mfma_f32_16x16x32_bf16(av[i], bh[j], acc[i][j], 0, 0, 0);
                acc[i][j] = __builtin_amdgcn_mfma_f32_16x16x32_bf16(av[i], bl[j], acc[i][j], 0, 0, 0);
            }
    }
#pragma unroll
    for (int i = 0; i < 4; ++i) {
        int m = m0 + wm + i * 16 + ((lane >> 4) << 2);
#pragma unroll
        for (int j = 0; j < 4; ++j) {
            int n = n0 + wn + j * 16 + (lane & 15);
#pragma unroll
            for (int rr = 0; rr < 4; ++rr)
                C[(size_t)(m + rr) * N + n] = f2bf(acc[i][j][rr]);
        }
    }
}

// ---------- persistent bidirectional LSTM recurrence, one layer ----------
// grid = 128 blocks: dir = blockIdx>>6, slice = blockIdx&63 -> hidden units [slice*8, slice*8+8)
// Whh slice resident in VGPRs as hi/lo MFMA B-fragments. h exchanged as hi/lo bf16 planes via
// LLC (agent-scope atomics), double-buffered.
// Sync: 256 per-(slice,wave) monotonic sub-flags per dir. Each wave publishes its own 8 batches
// directly from cell registers, drains its own vmcnt, then lane0 relaxed-stores its sub-flag
// (explicit waitcnt instead of ATOMIC_RELEASE: avoids conservative release codegen / L2 wb on
// the critical path, and removes the cross-wave barrier + LDS bounce from the signal path).
// xp is loaded per-thread into registers at loop top (issue-early / use-late) so no HBM-latency
// stall sits in front of the flag poll.
template <int LAYER>
__global__ __launch_bounds__(256, 1) void lstm_rec(
    const u16* __restrict__ xp_f, const u16* __restrict__ xp_b,
    const u16* __restrict__ whh_f_hi, const u16* __restrict__ whh_f_lo,
    const u16* __restrict__ whh_b_hi, const u16* __restrict__ whh_b_lo,
    const float* __restrict__ bih_f, const float* __restrict__ bhh_f,
    const float* __restrict__ bih_b, const float* __restrict__ bhh_b,
    u16* __restrict__ out0, float* __restrict__ pooled, const int* __restrict__ mask,
    u16* hbuf, u32* cnt)
{
    const int HP = 524;                              // padded LDS row (u16): stride 262 dw == 6 mod 32
    __shared__ __align__(16) u16  sHhi[32 * 524];    // h hi plane
    __shared__ __align__(16) u16  sHlo[32 * 524];    // h lo plane
    __shared__ __align__(16) float sG[32 * 33];      // gate pre-activations

    const int tid = threadIdx.x;
    const int dir = blockIdx.x >> 6;
    const int slice = blockIdx.x & 63;
    const u16* xp     = dir ? xp_b : xp_f;
    const u16* whhH   = dir ? whh_b_hi : whh_f_hi;
    const u16* whhL   = dir ? whh_b_lo : whh_f_lo;
    const float* bih  = dir ? bih_b : bih_f;
    const float* bhh  = dir ? bhh_b : bhh_f;
    // per dir: 2 bufs x 2 planes x 32*512 u16
    u16* hbD = hbuf + dir * 65536;
    u32* myFlags = cnt + dir * 256;                  // 256 per-(slice,wave) monotonic sub-flags

    const int wave = tid >> 6, lane = tid & 63;
    const int wm = (wave >> 1) * 16;          // batch half
    const int wn = (wave & 1) * 16;           // gate-col half
    bf16x8 wfragH[16], wfragL[16];
    {
        int n = wn + (lane & 15);
        int q = n >> 3, rr = n & 7;
        size_t rowoff = (size_t)(q * 512 + slice * 8 + rr) * 512 + (lane >> 4) * 8;
        const u16* wrh = whhH + rowoff;
        const u16* wrl = whhL + rowoff;
#pragma unroll
        for (int k2 = 0; k2 < 16; ++k2) {
            wfragH[k2] = *(const bf16x8*)(wrh + k2 * 32);
            wfragL[k2] = *(const bf16x8*)(wrl + k2 * 32);
        }
    }
    const int b = tid >> 3, r = tid & 7;      // cell-phase mapping (wave covers b in [wave*8, wave*8+8))
    float bias[4];
#pragma unroll
    for (int q = 0; q < 4; ++q) {
        int g = q * 512 + slice * 8 + r;
        bias[q] = bih[g] + bhh[g];
    }
    float cstate = 0.f, pool = 0.f;
    const int aoff = (wm + (lane & 15)) * HP + (lane >> 4) * 8;
    const int gRow = wm + ((lane >> 4) << 2), gCol = wn + (lane & 15);
    const int srow = tid >> 3, sc = tid & 7;  // stage mapping
    const u16* xpBase = xp + (size_t)(b * 512) * 2048 + slice * 8 + r;

    for (int t = 0; t < 512; ++t) {
        const int tt = dir ? (511 - t) : t;
        // 1. issue xp loads for this step into registers (consumed at cell, ~3us later)
        const u16* xrow = xpBase + (size_t)tt * 2048;
        u16 xv0 = xrow[0], xv1 = xrow[512], xv2 = xrow[1024], xv3 = xrow[1536];
        // 2. wave 0 polls the 256 sub-flags of this dir for h_{t-1} (4 flags per lane, 2 u64 loads)
        if (t > 0 && tid < 64) {
            const u32 tgt = (u32)t;
            const u64* fp = (const u64*)(myFlags + tid * 4);
            for (;;) {
                u64 f01 = __hip_atomic_load(fp,     __ATOMIC_RELAXED, __HIP_MEMORY_SCOPE_AGENT);
                u64 f23 = __hip_atomic_load(fp + 1, __ATOMIC_RELAXED, __HIP_MEMORY_SCOPE_AGENT);
                int ok = ((u32)f01 >= tgt) & ((u32)(f01 >> 32) >= tgt) &
                         ((u32)f23 >= tgt) & ((u32)(f23 >> 32) >= tgt);
                if (__all(ok)) break;
                __builtin_amdgcn_s_sleep(1);
            }
        }
        __syncthreads();                       // B1: all h_{t-1} published
        if (t > 0) {
            // 3. stage h hi/lo planes: issue ALL 32 loads first, then all LDS writes
            const u16* hp = hbD + ((t - 1) & 1) * 32768 + srow * 512;   // hi plane row
            const u16* lp = hp + 16384;                                  // lo plane row
            u16* dhi = sHhi + srow * HP;
            u16* dlo = sHlo + srow * HP;
            u64 rh[16], rl[16];
#pragma unroll
            for (int j = 0; j < 8; ++j) {
                int ch = sc + 8 * j;              // chunk of 8 u16 (16B)
                rh[2*j]   = __hip_atomic_load((const u64*)(hp + ch * 8),     __ATOMIC_RELAXED, __HIP_MEMORY_SCOPE_AGENT);
                rh[2*j+1] = __hip_atomic_load((const u64*)(hp + ch * 8) + 1, __ATOMIC_RELAXED, __HIP_MEMORY_SCOPE_AGENT);
                rl[2*j]   = __hip_atomic_load((const u64*)(lp + ch * 8),     __ATOMIC_RELAXED, __HIP_MEMORY_SCOPE_AGENT);
                rl[2*j+1] = __hip_atomic_load((const u64*)(lp + ch * 8) + 1, __ATOMIC_RELAXED, __HIP_MEMORY_SCOPE_AGENT);
            }
#pragma unroll
            for (int j = 0; j < 8; ++j) {
                int ch = sc + 8 * j;
                *(u64*)(dhi + ch * 8)     = rh[2*j];
                *(u64*)(dhi + ch * 8 + 4) = rh[2*j+1];
                *(u64*)(dlo + ch * 8)     = rl[2*j];
                *(u64*)(dlo + ch * 8 + 4) = rl[2*j+1];
            }
        }
        __syncthreads();                       // B2: h staged
        // 4. G = h @ Whh_slice^T, hi/lo split, 3 independent accumulator chains
        f32x4 ac0 = {}, ac1 = {}, ac2 = {};
        if (t > 0) {
#pragma unroll
            for (int k2 = 0; k2 < 16; ++k2) {
                bf16x8 ah = *(const bf16x8*)(sHhi + aoff + k2 * 32);
                bf16x8 al = *(const bf16x8*)(sHlo + aoff + k2 * 32);
                ac0 = __builtin_amdgcn_mfma_f32_16x16x32_bf16(ah, wfragH[k2], ac0, 0, 0, 0);
                ac1 = __builtin_amdgcn_mfma_f32_16x16x32_bf16(al, wfragH[k2], ac1, 0, 0, 0);
                ac2 = __builtin_amdgcn_mfma_f32_16x16x32_bf16(ah, wfragL[k2], ac2, 0, 0, 0);
            }
        }
#pragma unroll
        for (int rr = 0; rr < 4; ++rr) sG[(gRow + rr) * 33 + gCol] = ac0[rr] + ac1[rr] + ac2[rr];
        __syncthreads();                       // B3: gates ready
        // 5. LSTM cell (fp32) + direct per-wave publish
        {
            float gq[4];
            gq[0] = sG[b * 33 + 0 * 8 + r] + bf2f(xv0) + bias[0];
            gq[1] = sG[b * 33 + 1 * 8 + r] + bf2f(xv1) + bias[1];
            gq[2] = sG[b * 33 + 2 * 8 + r] + bf2f(xv2) + bias[2];
            gq[3] = sG[b * 33 + 3 * 8 + r] + bf2f(xv3) + bias[3];
            float ig = sigmoidf(gq[0]), fg = sigmoidf(gq[1]);
            float gg = tanh_safe(gq[2]), og = sigmoidf(gq[3]);
            cstate = fg * cstate + ig * gg;
            float h = og * tanh_safe(cstate);
            u16 hh = f2bf(h);
            u16 hl = f2bf(h - bf2f(hh));
            if (LAYER == 0) {
                out0[((size_t)(b * 512 + tt)) * 1024 + dir * 512 + slice * 8 + r] = hh;
            } else {
                pool += h * (float)mask[b * 512 + tt];
            }
            // 6. publish own h element (both planes), per-wave completion, relaxed sub-flag
            u16* gh = hbD + (t & 1) * 32768 + b * 512 + slice * 8 + r;
            __hip_atomic_store(gh,         hh, __ATOMIC_RELAXED, __HIP_MEMORY_SCOPE_AGENT);
            __hip_atomic_store(gh + 16384, hl, __ATOMIC_RELAXED, __HIP_MEMORY_SCOPE_AGENT);
            asm volatile("s_waitcnt vmcnt(0)" ::: "memory");
            if ((tid & 63) == 0)
                __hip_atomic_store(myFlags + slice * 4 + wave, (u32)(t + 1),
                                   __ATOMIC_RELAXED, __HIP_MEMORY_SCOPE_AGENT);
        }
        // no trailing barrier: next iteration's B1 re-syncs before LDS reuse
    }
    if (LAYER == 1)
        pooled[(size_t)b * 1024 + dir * 512 + slice * 8 + r] = pool;
}

// ---------- final: logits = (pooled/msum) @ fcW^T + fcb ----------
__global__ __launch_bounds__(256) void final_fc(const float* __restrict__ pooled, const int* __restrict__ mask,
                                                const float* __restrict__ fcW, const float* __restrict__ fcb,
                                                float* __restrict__ out) {
    __shared__ float red[256];
    int tid = threadIdx.x;
    int pair = tid & 63, kc = tid >> 6;
    int b = pair >> 1, c = pair & 1;
    float s = 0.f;
    for (int k = kc * 256; k < kc * 256 + 256; ++k)
        s += pooled[b * 1024 + k] * fcW[c * 1024 + k];
    red[tid] = s;
    __syncthreads();
    if (kc == 0) {
        float tot = red[pair] + red[64 + pair] + red[128 + pair] + red[192 + pair];
        float ms = 0.f;
        for (int t = 0; t < 512; ++t) ms += (float)mask[b * 512 + t];
        ms = fmaxf(ms, 1e-9f);
        out[b * 2 + c] = tot / ms + fcb[c];
    }
}

extern "C" void kernel_launch(void* const* d_in, const int* in_sizes, int n_in,
                              void* d_out, int out_size, void* d_ws, size_t ws_size,
                              hipStream_t stream) {
    (void)in_sizes; (void)n_in; (void)out_size; (void)ws_size;
    const int*   x     = (const int*)d_in[0];
    const int*   amask = (const int*)d_in[1];
    const float* emb   = (const float*)d_in[2];
    const float* fcW   = (const float*)d_in[3];
    const float* fcb   = (const float*)d_in[4];
    const float* fWih0 = (const float*)d_in[5];
    const float* fWhh0 = (const float*)d_in[6];
    const float* fbih0 = (const float*)d_in[7];
    const float* fbhh0 = (const float*)d_in[8];
    const float* bWih0 = (const float*)d_in[9];
    const float* bWhh0 = (const float*)d_in[10];
    const float* bbih0 = (const float*)d_in[11];
    const float* bbhh0 = (const float*)d_in[12];
    const float* fWih1 = (const float*)d_in[13];
    const float* fWhh1 = (const float*)d_in[14];
    const float* fbih1 = (const float*)d_in[15];
    const float* fbhh1 = (const float*)d_in[16];
    const float* bWih1 = (const float*)d_in[17];
    const float* bWhh1 = (const float*)d_in[18];
    const float* bbih1 = (const float*)d_in[19];
    const float* bbhh1 = (const float*)d_in[20];

    char* ws = (char*)d_ws;
    size_t off = 0;
    auto alloc = [&](size_t bytes) { void* p = ws + off; off += (bytes + 1023) & ~(size_t)1023; return p; };
    u16* x0    = (u16*)alloc((size_t)16384 * 512 * 2);
    u16* xpf   = (u16*)alloc((size_t)16384 * 2048 * 2);
    u16* xpb   = (u16*)alloc((size_t)16384 * 2048 * 2);
    u16* out0  = (u16*)alloc((size_t)16384 * 1024 * 2);
    u16* wih0fH = (u16*)alloc((size_t)2048 * 512 * 2);
    u16* wih0fL = (u16*)alloc((size_t)2048 * 512 * 2);
    u16* wih0bH = (u16*)alloc((size_t)2048 * 512 * 2);
    u16* wih0bL = (u16*)alloc((size_t)2048 * 512 * 2);
    u16* whh0fH = (u16*)alloc((size_t)2048 * 512 * 2);
    u16* whh0fL = (u16*)alloc((size_t)2048 * 512 * 2);
    u16* whh0bH = (u16*)alloc((size_t)2048 * 512 * 2);
    u16* whh0bL = (u16*)alloc((size_t)2048 * 512 * 2);
    u16* wih1fH = (u16*)alloc((size_t)2048 * 1024 * 2);
    u16* wih1fL = (u16*)alloc((size_t)2048 * 1024 * 2);
    u16* wih1bH = (u16*)alloc((size_t)2048 * 1024 * 2);
    u16* wih1bL = (u16*)alloc((size_t)2048 * 1024 * 2);
    u16* whh1fH = (u16*)alloc((size_t)2048 * 512 * 2);
    u16* whh1fL = (u16*)alloc((size_t)2048 * 512 * 2);
    u16* whh1bH = (u16*)alloc((size_t)2048 * 512 * 2);
    u16* whh1bL = (u16*)alloc((size_t)2048 * 512 * 2);
    float* pooled = (float*)alloc((size_t)32 * 1024 * 4);
    u16* hbuf  = (u16*)alloc((size_t)2 * 2 * 2 * 32 * 512 * 2);   // dirs x bufs x planes
    u32* cnt   = (u32*)alloc(4096);                               // sub-flags: 2 layers x 2 dirs x 256

    hipMemsetAsync(cnt, 0, 4096, stream);

    const int NW0 = 2048 * 512, NW1 = 2048 * 1024;
    castk2<<<dim3((NW0 + 255) / 256), 256, 0, stream>>>(fWih0, wih0fH, wih0fL, NW0);
    castk2<<<dim3((NW0 + 255) / 256), 256, 0, stream>>>(bWih0, wih0bH, wih0bL, NW0);
    castk2<<<dim3((NW0 + 255) / 256), 256, 0, stream>>>(fWhh0, whh0fH, whh0fL, NW0);
    castk2<<<dim3((NW0 + 255) / 256), 256, 0, stream>>>(bWhh0, whh0bH, whh0bL, NW0);
    castk2<<<dim3((NW1 + 255) / 256), 256, 0, stream>>>(fWih1, wih1fH, wih1fL, NW1);
    castk2<<<dim3((NW1 + 255) / 256), 256, 0, stream>>>(bWih1, wih1bH, wih1bL, NW1);
    castk2<<<dim3((NW0 + 255) / 256), 256, 0, stream>>>(fWhh1, whh1fH, whh1fL, NW0);
    castk2<<<dim3((NW0 + 255) / 256), 256, 0, stream>>>(bWhh1, whh1bH, whh1bL, NW0);

    embed_cast<<<dim3(16384), 256, 0, stream>>>(x, emb, x0);

    // layer 0 input projections: [16384,512] @ [2048,512]^T
    gemm_bt<<<dim3(16, 128), 256, 0, stream>>>(x0, wih0fH, wih0fL, xpf, 16384, 2048, 512);
    gemm_bt<<<dim3(16, 128), 256, 0, stream>>>(x0, wih0bH, wih0bL, xpb, 16384, 2048, 512);
    // layer 0 recurrence
    lstm_rec<0><<<dim3(128), 256, 0, stream>>>(xpf, xpb, whh0fH, whh0fL, whh0bH, whh0bL,
                                               fbih0, fbhh0, bbih0, bbhh0,
                                               out0, nullptr, nullptr, hbuf, cnt);
    // layer 1 input projections: [16384,1024] @ [2048,1024]^T
    gemm_bt<<<dim3(16, 128), 256, 0, stream>>>(out0, wih1fH, wih1fL, xpf, 16384, 2048, 1024);
    gemm_bt<<<dim3(16, 128), 256, 0, stream>>>(out0, wih1bH, wih1bL, xpb, 16384, 2048, 1024);
    // layer 1 recurrence + pooling
    lstm_rec<1><<<dim3(128), 256, 0, stream>>>(xpf, xpb, whh1fH, whh1fL, whh1bH, whh1bL,
                                               fbih1, fbhh1, bbih1, bbhh1,
                                               nullptr, pooled, amask, hbuf, cnt + 512);

    final_fc<<<dim3(1), 256, 0, stream>>>(pooled, amask, fcW, fcb, (float*)d_out);
}